// Round 5
// baseline (1972.790 us; speedup 1.0000x reference)
//
#include <hip/hip_runtime.h>

#define R 5
#define U 100000
#define M 50000
#define E 2000000
#define F 10
#define D 50

#define TE (R * E)                      // 10,000,000 edges per direction
#define NBLK 256                        // phase A/C block count
#define CHUNK ((TE + NBLK - 1) / NBLK)  // 39,063 edges per block
#define BSZ 256

#define KS_U (R * U)                    // 500,000 user keys
#define KS_I (R * M)                    // 250,000 item keys
#define NBU_U ((KS_U + 255) / 256)      // 1954 user buckets
#define NBU_I ((KS_I + 255) / 256)      // 977 item buckets
#define NBU_T (NBU_U + NBU_I)           // 2931
#define OFFI (NBU_U * NBLK)             // 500,224 (item region start in ghist/S)
#define GTOT (OFFI + NBU_I * NBLK)      // 750,336
#define NS1 ((GTOT + 1023) / 1024)      // 733 scan blocks

// ======================= bucketed counting-sort path =======================

// Per-block LDS histogram over both directions' buckets. No global atomics.
__global__ __launch_bounds__(BSZ) void phaseA(const int* __restrict__ esrc,
                                              const int* __restrict__ edst,
                                              unsigned* __restrict__ ghist) {
    __shared__ unsigned hist[NBU_T];
    for (int i = threadIdx.x; i < NBU_T; i += BSZ) hist[i] = 0;
    __syncthreads();
    int b = blockIdx.x;
    int lo = b * CHUNK, hi = min(lo + CHUNK, TE);
    for (int i = lo + threadIdx.x; i < hi; i += BSZ) {
        unsigned r = (unsigned)i / (unsigned)E;
        int s = esrc[i], d = edst[i];
        unsigned ku = r * U + (unsigned)s;
        unsigned ki = r * M + (unsigned)d;
        atomicAdd(&hist[ku >> 8], 1u);
        atomicAdd(&hist[NBU_U + (ki >> 8)], 1u);
    }
    __syncthreads();
    for (int j = threadIdx.x; j < NBU_T; j += BSZ) {
        unsigned idx = (j < NBU_U) ? (unsigned)j * NBLK + b
                                   : OFFI + (unsigned)(j - NBU_U) * NBLK + b;
        ghist[idx] = hist[j];
    }
}

// Exclusive scan, 3 kernels. scan1: per-1024-chunk scan + chunk totals.
__global__ __launch_bounds__(BSZ) void scan1(const unsigned* __restrict__ g,
                                             unsigned* __restrict__ S,
                                             unsigned* __restrict__ psum) {
    __shared__ unsigned sh[BSZ];
    int base = blockIdx.x * 1024 + threadIdx.x * 4;
    unsigned v[4], tsum = 0;
    for (int k = 0; k < 4; k++) {
        int i = base + k;
        v[k] = (i < GTOT) ? g[i] : 0u;
        tsum += v[k];
    }
    sh[threadIdx.x] = tsum;
    __syncthreads();
    for (int off = 1; off < BSZ; off <<= 1) {
        unsigned t = (threadIdx.x >= off) ? sh[threadIdx.x - off] : 0u;
        __syncthreads();
        sh[threadIdx.x] += t;
        __syncthreads();
    }
    unsigned ex = sh[threadIdx.x] - tsum;
    for (int k = 0; k < 4; k++) {
        int i = base + k;
        if (i < GTOT) S[i] = ex;
        ex += v[k];
    }
    if (threadIdx.x == BSZ - 1) psum[blockIdx.x] = sh[BSZ - 1];
}

__global__ __launch_bounds__(BSZ) void scan2(unsigned* __restrict__ psum) {
    __shared__ unsigned sh[BSZ];
    unsigned v[3], tsum = 0;
    int base = threadIdx.x * 3;
    for (int k = 0; k < 3; k++) {
        int i = base + k;
        v[k] = (i < NS1) ? psum[i] : 0u;
        tsum += v[k];
    }
    sh[threadIdx.x] = tsum;
    __syncthreads();
    for (int off = 1; off < BSZ; off <<= 1) {
        unsigned t = (threadIdx.x >= off) ? sh[threadIdx.x - off] : 0u;
        __syncthreads();
        sh[threadIdx.x] += t;
        __syncthreads();
    }
    unsigned ex = sh[threadIdx.x] - tsum;
    for (int k = 0; k < 3; k++) {
        int i = base + k;
        if (i < NS1) psum[i] = ex;
        ex += v[k];
    }
}

__global__ __launch_bounds__(BSZ) void scan3(unsigned* __restrict__ S,
                                             const unsigned* __restrict__ psum) {
    unsigned add = psum[blockIdx.x];
    int base = blockIdx.x * 1024 + threadIdx.x * 4;
    for (int k = 0; k < 4; k++) {
        int i = base + k;
        if (i < GTOT) S[i] += add;
    }
}

// Scatter edges into bucket-grouped payload array. LDS cursor atomics only.
// payload = local_node(8b) | src_id(<<8): src<100K fits 17 bits -> 25 bits.
__global__ __launch_bounds__(BSZ) void phaseC(const int* __restrict__ esrc,
                                              const int* __restrict__ edst,
                                              const unsigned* __restrict__ S,
                                              unsigned* __restrict__ sorted) {
    __shared__ unsigned cur[NBU_T];
    int b = blockIdx.x;
    for (int j = threadIdx.x; j < NBU_T; j += BSZ) {
        unsigned idx = (j < NBU_U) ? (unsigned)j * NBLK + b
                                   : OFFI + (unsigned)(j - NBU_U) * NBLK + b;
        cur[j] = S[idx];
    }
    __syncthreads();
    int lo = b * CHUNK, hi = min(lo + CHUNK, TE);
    for (int i = lo + threadIdx.x; i < hi; i += BSZ) {
        unsigned r = (unsigned)i / (unsigned)E;
        int s = esrc[i], d = edst[i];
        unsigned ku = r * U + (unsigned)s;
        unsigned ki = r * M + (unsigned)d;
        unsigned pu = atomicAdd(&cur[ku >> 8], 1u);
        sorted[pu] = (ku & 255u) | ((unsigned)d << 8);   // user list: src=item id
        unsigned pi = atomicAdd(&cur[NBU_U + (ki >> 8)], 1u);
        sorted[pi] = (ki & 255u) | ((unsigned)s << 8);   // item list: src=user id
    }
}

// One block per bucket: LDS-accumulate neighbor sums, then fused projection.
// v2: XCD-aware bucket swizzle (contiguous bucket chunk per XCD -> the 2-4MB
// relation table a chunk gathers from stays L2-resident), 2-edge unroll with
// loads hoisted above the LDS atomics, and a per-local r*NSRC LDS table to
// kill the per-edge runtime integer division.
__global__ __launch_bounds__(BSZ) void phaseD(
    const unsigned* __restrict__ sorted, const unsigned* __restrict__ S,
    const float* __restrict__ fsrc_u, const float* __restrict__ fdst_u,
    const float* __restrict__ wsf_u, const float* __restrict__ wnf_u,
    const float* __restrict__ bia_u,
    const float* __restrict__ fsrc_i, const float* __restrict__ fdst_i,
    const float* __restrict__ wsf_i, const float* __restrict__ wnf_i,
    const float* __restrict__ bia_i,
    float* __restrict__ out_u, float* __restrict__ out_i) {
    __shared__ float acc[256 * F];
    __shared__ float cnt[256];
    __shared__ unsigned rbase[256];  // r(local) * NSRC

    // bijective XCD swizzle (m204): MI355X dispatches blockIdx round-robin
    // over 8 XCDs; give XCD x the contiguous bucket range so its gathers hit
    // the same relation table repeatedly.
    unsigned orig = blockIdx.x;
    const unsigned q = NBU_T / 8u, rem = NBU_T % 8u;
    unsigned xcd = orig & 7u, off = orig >> 3;
    unsigned bkt = (xcd < rem ? xcd * (q + 1u) : rem * (q + 1u) + (xcd - rem) * q) + off;

    bool isU = bkt < NBU_U;
    int j = isU ? (int)bkt : (int)bkt - NBU_U;
    unsigned N = isU ? U : M;
    unsigned NSRC = isU ? M : U;  // src feature table rows per relation
    const float* fsrc = isU ? fsrc_u : fsrc_i;

    unsigned sbase = isU ? 0u : (unsigned)OFFI;
    unsigned lo = S[sbase + (unsigned)j * NBLK];
    unsigned hi = (!isU && j + 1 == NBU_I) ? (unsigned)(2 * TE)
                                           : S[sbase + (unsigned)(j + 1) * NBLK];

    for (int t = threadIdx.x; t < 256 * F; t += BSZ) acc[t] = 0.f;
    unsigned keybase = (unsigned)j * 256u;
    {
        // one thread per local node (BSZ == 256)
        int t = threadIdx.x;
        cnt[t] = 0.f;
        unsigned key = keybase + (unsigned)t;
        unsigned r = (key < (unsigned)R * N) ? key / N : 0u;
        rbase[t] = r * NSRC;
    }
    __syncthreads();

    unsigned e = lo + threadIdx.x;
    for (; e + BSZ < hi; e += 2u * BSZ) {
        unsigned pay0 = sorted[e];
        unsigned pay1 = sorted[e + BSZ];
        unsigned l0 = pay0 & 255u, s0 = pay0 >> 8;
        unsigned l1 = pay1 & 255u, s1 = pay1 >> 8;
        const float2* row0 = (const float2*)(fsrc + (size_t)(rbase[l0] + s0) * F);
        const float2* row1 = (const float2*)(fsrc + (size_t)(rbase[l1] + s1) * F);
        float2 v0[5], v1[5];
#pragma unroll
        for (int k = 0; k < 5; k++) v0[k] = row0[k];
#pragma unroll
        for (int k = 0; k < 5; k++) v1[k] = row1[k];
        float* a0 = acc + l0 * F;
        float* a1 = acc + l1 * F;
#pragma unroll
        for (int k = 0; k < 5; k++) {
            atomicAdd(a0 + 2 * k, v0[k].x);
            atomicAdd(a0 + 2 * k + 1, v0[k].y);
        }
        atomicAdd(&cnt[l0], 1.f);
#pragma unroll
        for (int k = 0; k < 5; k++) {
            atomicAdd(a1 + 2 * k, v1[k].x);
            atomicAdd(a1 + 2 * k + 1, v1[k].y);
        }
        atomicAdd(&cnt[l1], 1.f);
    }
    if (e < hi) {
        unsigned pay = sorted[e];
        unsigned local = pay & 255u;
        unsigned src = pay >> 8;
        const float2* row = (const float2*)(fsrc + (size_t)(rbase[local] + src) * F);
        float* a = acc + local * F;
#pragma unroll
        for (int k = 0; k < 5; k++) {
            float2 v = row[k];
            atomicAdd(a + 2 * k, v.x);
            atomicAdd(a + 2 * k + 1, v.y);
        }
        atomicAdd(&cnt[local], 1.f);
    }
    __syncthreads();

    const float* fdst = isU ? fdst_u : fdst_i;
    const float* wsf = isU ? wsf_u : wsf_i;
    const float* wnf = isU ? wnf_u : wnf_i;
    const float* bia = isU ? bia_u : bia_i;
    float* out = isU ? out_u : out_i;

    for (int o = threadIdx.x; o < 256 * D; o += BSZ) {
        int local = o / D, d = o - local * D;
        unsigned key = keybase + (unsigned)local;
        if (key >= (unsigned)(R)*N) continue;  // tail bucket beyond keyspace
        unsigned r = key / N, n = key - r * N;
        float inv = 1.f / fmaxf(cnt[local], 1.f);
        const float* fd = fdst + ((size_t)r * N + n) * F;
        const float* a = acc + local * F;
        const float* wsp = wsf + (size_t)r * F * D + d;
        const float* wnp = wnf + (size_t)r * F * D + d;
        float o1 = bia[r * D + d], o2 = 0.f;
#pragma unroll
        for (int f = 0; f < F; f++) {
            o1 += fd[f] * wsp[(size_t)f * D];
            o2 += a[f] * wnp[(size_t)f * D];
        }
        out[(size_t)n * (R * D) + r * D + d] = o1 + o2 * inv;
    }
}

// ======================= round-1 fallback (small ws) =======================
#define SUM_I_OFF 0
#define CNT_I_OFF ((size_t)R * M * F)
#define SUM_U_OFF (CNT_I_OFF + (size_t)R * M)
#define CNT_U_OFF (SUM_U_OFF + (size_t)R * U * F)
#define WS_FLOATS (CNT_U_OFF + (size_t)R * U)

__global__ void scatter_edges(const int* __restrict__ esrc, const int* __restrict__ edst,
                              const float* __restrict__ feat_u_fwd,
                              const float* __restrict__ feat_i_rev, float* __restrict__ ws) {
    float* sum_i = ws + SUM_I_OFF;
    float* cnt_i = ws + CNT_I_OFF;
    float* sum_u = ws + SUM_U_OFF;
    float* cnt_u = ws + CNT_U_OFF;
    const int total = R * E;
    for (int idx = blockIdx.x * blockDim.x + threadIdx.x; idx < total;
         idx += gridDim.x * blockDim.x) {
        int r = idx / E;
        int s = esrc[idx], d = edst[idx];
        const float* fu = feat_u_fwd + ((size_t)r * U + s) * F;
        const float* fi = feat_i_rev + ((size_t)r * M + d) * F;
        float* si = sum_i + ((size_t)r * M + d) * F;
        float* su = sum_u + ((size_t)r * U + s) * F;
#pragma unroll
        for (int f = 0; f < F; ++f) {
            atomicAdd(si + f, fu[f]);
            atomicAdd(su + f, fi[f]);
        }
        atomicAdd(cnt_i + (size_t)r * M + d, 1.0f);
        atomicAdd(cnt_u + (size_t)r * U + s, 1.0f);
    }
}

__global__ void finalize_nodes(int N, const float* __restrict__ feat_dst,
                               const float* __restrict__ w_self, const float* __restrict__ w_neigh,
                               const float* __restrict__ bias, const float* __restrict__ sum,
                               const float* __restrict__ cnt, float* __restrict__ out) {
    int idx = blockIdx.x * blockDim.x + threadIdx.x;
    int total = N * R * D;
    if (idx >= total) return;
    int n = idx / (R * D);
    int rd = idx - n * (R * D);
    int r = rd / D;
    int d = rd - r * D;
    const float* fd = feat_dst + ((size_t)r * N + n) * F;
    const float* sn = sum + ((size_t)r * N + n) * F;
    float inv = 1.0f / fmaxf(cnt[(size_t)r * N + n], 1.0f);
    const float* wsp = w_self + (size_t)r * F * D + d;
    const float* wnp = w_neigh + (size_t)r * F * D + d;
    float acc_self = bias[r * D + d];
    float acc_n = 0.0f;
#pragma unroll
    for (int f = 0; f < F; ++f) {
        acc_self += fd[f] * wsp[(size_t)f * D];
        acc_n += sn[f] * wnp[(size_t)f * D];
    }
    out[idx] = acc_self + acc_n * inv;
}

// ======================= launch =======================
extern "C" void kernel_launch(void* const* d_in, const int* in_sizes, int n_in,
                              void* d_out, int out_size, void* d_ws, size_t ws_size,
                              hipStream_t stream) {
    const int* edges_src = (const int*)d_in[0];
    const int* edges_dst = (const int*)d_in[1];
    const float* feat_u_fwd = (const float*)d_in[2];
    const float* feat_i_fwd = (const float*)d_in[3];
    const float* feat_i_rev = (const float*)d_in[4];
    const float* feat_u_rev = (const float*)d_in[5];
    const float* w_self_fwd = (const float*)d_in[6];
    const float* w_neigh_fwd = (const float*)d_in[7];
    const float* b_fwd = (const float*)d_in[8];
    const float* w_self_rev = (const float*)d_in[9];
    const float* w_neigh_rev = (const float*)d_in[10];
    const float* b_rev = (const float*)d_in[11];

    float* out = (float*)d_out;
    float* out_u = out;
    float* out_i = out + (size_t)U * R * D;

    size_t need = ((size_t)2 * TE + 2ull * GTOT + 1024ull) * 4ull;  // ~86 MB
    if (ws_size >= need) {
        unsigned* sorted = (unsigned*)d_ws;            // 2*TE
        unsigned* ghist = sorted + (size_t)2 * TE;     // GTOT
        unsigned* S = ghist + GTOT;                    // GTOT
        unsigned* psum = S + GTOT;                     // 1024

        phaseA<<<NBLK, BSZ, 0, stream>>>(edges_src, edges_dst, ghist);
        scan1<<<NS1, BSZ, 0, stream>>>(ghist, S, psum);
        scan2<<<1, BSZ, 0, stream>>>(psum);
        scan3<<<NS1, BSZ, 0, stream>>>(S, psum);
        phaseC<<<NBLK, BSZ, 0, stream>>>(edges_src, edges_dst, S, sorted);
        phaseD<<<NBU_T, BSZ, 0, stream>>>(sorted, S,
                                          feat_i_rev, feat_u_rev, w_self_rev, w_neigh_rev, b_rev,
                                          feat_u_fwd, feat_i_fwd, w_self_fwd, w_neigh_fwd, b_fwd,
                                          out_u, out_i);
    } else {
        // fallback: round-1 global-atomic path
        float* ws = (float*)d_ws;
        hipMemsetAsync(d_ws, 0, WS_FLOATS * sizeof(float), stream);
        scatter_edges<<<4096, 256, 0, stream>>>(edges_src, edges_dst, feat_u_fwd, feat_i_rev, ws);
        finalize_nodes<<<(U * R * D + 255) / 256, 256, 0, stream>>>(
            U, feat_u_rev, w_self_rev, w_neigh_rev, b_rev, ws + SUM_U_OFF, ws + CNT_U_OFF, out_u);
        finalize_nodes<<<(M * R * D + 255) / 256, 256, 0, stream>>>(
            M, feat_i_fwd, w_self_fwd, w_neigh_fwd, b_fwd, ws + SUM_I_OFF, ws + CNT_I_OFF, out_i);
    }
}

// Round 6
// 1433.690 us; speedup vs baseline: 1.3760x; 1.3760x over previous
//
#include <hip/hip_runtime.h>

#define R 5
#define U 100000
#define M 50000
#define E 2000000
#define F 10
#define D 50

#define TE (R * E)                      // 10,000,000 edges per direction
#define NBLK 256                        // phase A/C block count
#define CHUNK ((TE + NBLK - 1) / NBLK)  // 39,063 edges per block
#define BSZ 256

#define NKEY 128                        // keys per bucket (local id fits 7 bits)
#define KS_U (R * U)                    // 500,000 user keys
#define KS_I (R * M)                    // 250,000 item keys
#define NBU_U ((KS_U + NKEY - 1) / NKEY)  // 3907 user buckets
#define NBU_I ((KS_I + NKEY - 1) / NKEY)  // 1954 item buckets
#define NBU_T (NBU_U + NBU_I)             // 5861
#define OFFI (NBU_U * NBLK)               // item region start in S
#define GTOT (OFFI + NBU_I * NBLK)        // 1,500,416
#define NS1 ((GTOT + 1023) / 1024)        // 1466 scan blocks
#define S2K ((NS1 + 255) / 256)           // 6 entries/thread in scan2

// ======================= bucketed counting-sort path =======================

// Per-block LDS histogram over both directions' buckets. No global atomics.
__global__ __launch_bounds__(BSZ) void phaseA(const int* __restrict__ esrc,
                                              const int* __restrict__ edst,
                                              unsigned* __restrict__ ghist) {
    __shared__ unsigned hist[NBU_T];
    for (int i = threadIdx.x; i < NBU_T; i += BSZ) hist[i] = 0;
    __syncthreads();
    int b = blockIdx.x;
    int lo = b * CHUNK, hi = min(lo + CHUNK, TE);
    for (int i = lo + threadIdx.x; i < hi; i += BSZ) {
        unsigned r = (unsigned)i / (unsigned)E;
        int s = esrc[i], d = edst[i];
        unsigned ku = r * U + (unsigned)s;
        unsigned ki = r * M + (unsigned)d;
        atomicAdd(&hist[ku >> 7], 1u);
        atomicAdd(&hist[NBU_U + (ki >> 7)], 1u);
    }
    __syncthreads();
    for (int j = threadIdx.x; j < NBU_T; j += BSZ) {
        unsigned idx = (j < NBU_U) ? (unsigned)j * NBLK + b
                                   : OFFI + (unsigned)(j - NBU_U) * NBLK + b;
        ghist[idx] = hist[j];
    }
}

// Exclusive scan over ghist IN PLACE (S == ghist), 3 kernels.
__global__ __launch_bounds__(BSZ) void scan1(unsigned* __restrict__ S,
                                             unsigned* __restrict__ psum) {
    __shared__ unsigned sh[BSZ];
    int base = blockIdx.x * 1024 + threadIdx.x * 4;
    unsigned v[4], tsum = 0;
    for (int k = 0; k < 4; k++) {
        int i = base + k;
        v[k] = (i < GTOT) ? S[i] : 0u;
        tsum += v[k];
    }
    sh[threadIdx.x] = tsum;
    __syncthreads();
    for (int off = 1; off < BSZ; off <<= 1) {
        unsigned t = (threadIdx.x >= off) ? sh[threadIdx.x - off] : 0u;
        __syncthreads();
        sh[threadIdx.x] += t;
        __syncthreads();
    }
    unsigned ex = sh[threadIdx.x] - tsum;
    for (int k = 0; k < 4; k++) {
        int i = base + k;
        if (i < GTOT) S[i] = ex;
        ex += v[k];
    }
    if (threadIdx.x == BSZ - 1) psum[blockIdx.x] = sh[BSZ - 1];
}

__global__ __launch_bounds__(BSZ) void scan2(unsigned* __restrict__ psum) {
    __shared__ unsigned sh[BSZ];
    unsigned v[S2K], tsum = 0;
    int base = threadIdx.x * S2K;
    for (int k = 0; k < S2K; k++) {
        int i = base + k;
        v[k] = (i < NS1) ? psum[i] : 0u;
        tsum += v[k];
    }
    sh[threadIdx.x] = tsum;
    __syncthreads();
    for (int off = 1; off < BSZ; off <<= 1) {
        unsigned t = (threadIdx.x >= off) ? sh[threadIdx.x - off] : 0u;
        __syncthreads();
        sh[threadIdx.x] += t;
        __syncthreads();
    }
    unsigned ex = sh[threadIdx.x] - tsum;
    for (int k = 0; k < S2K; k++) {
        int i = base + k;
        if (i < NS1) psum[i] = ex;
        ex += v[k];
    }
}

__global__ __launch_bounds__(BSZ) void scan3(unsigned* __restrict__ S,
                                             const unsigned* __restrict__ psum) {
    unsigned add = psum[blockIdx.x];
    int base = blockIdx.x * 1024 + threadIdx.x * 4;
    for (int k = 0; k < 4; k++) {
        int i = base + k;
        if (i < GTOT) S[i] += add;
    }
}

// Scatter edges into bucket-grouped payload array. LDS cursor atomics only.
// payload = local_node(7b) | src_id(<<7): src<100K fits 17 bits -> 24 bits.
__global__ __launch_bounds__(BSZ) void phaseC(const int* __restrict__ esrc,
                                              const int* __restrict__ edst,
                                              const unsigned* __restrict__ S,
                                              unsigned* __restrict__ sorted) {
    __shared__ unsigned cur[NBU_T];
    int b = blockIdx.x;
    for (int j = threadIdx.x; j < NBU_T; j += BSZ) {
        unsigned idx = (j < NBU_U) ? (unsigned)j * NBLK + b
                                   : OFFI + (unsigned)(j - NBU_U) * NBLK + b;
        cur[j] = S[idx];
    }
    __syncthreads();
    int lo = b * CHUNK, hi = min(lo + CHUNK, TE);
    for (int i = lo + threadIdx.x; i < hi; i += BSZ) {
        unsigned r = (unsigned)i / (unsigned)E;
        int s = esrc[i], d = edst[i];
        unsigned ku = r * U + (unsigned)s;
        unsigned ki = r * M + (unsigned)d;
        unsigned pu = atomicAdd(&cur[ku >> 7], 1u);
        sorted[pu] = (ku & 127u) | ((unsigned)d << 7);   // user list: src=item id
        unsigned pi = atomicAdd(&cur[NBU_U + (ki >> 7)], 1u);
        sorted[pi] = (ki & 127u) | ((unsigned)s << 7);   // item list: src=user id
    }
}

// One block per bucket: LDS-accumulate neighbor sums, then fused projection.
// v3: per-DIRECTION bijective XCD swizzle (user and item bucket ranges each
// split evenly over the 8 XCDs -> balanced edges/XCD AND contiguous per-XCD
// table working set), 128-key buckets (finer tail, shorter chains), 4-deep
// gather unroll ahead of the LDS atomics.
__global__ __launch_bounds__(BSZ) void phaseD(
    const unsigned* __restrict__ sorted, const unsigned* __restrict__ S,
    const float* __restrict__ fsrc_u, const float* __restrict__ fdst_u,
    const float* __restrict__ wsf_u, const float* __restrict__ wnf_u,
    const float* __restrict__ bia_u,
    const float* __restrict__ fsrc_i, const float* __restrict__ fdst_i,
    const float* __restrict__ wsf_i, const float* __restrict__ wnf_i,
    const float* __restrict__ bia_i,
    float* __restrict__ out_u, float* __restrict__ out_i) {
    __shared__ float acc[NKEY * F];
    __shared__ float cnt[NKEY];
    __shared__ unsigned rbase[NKEY];  // r(local) * NSRC

    // per-direction bijective XCD swizzle (m204 form). Dispatch round-robins
    // blockIdx over 8 XCDs; map each XCD's blocks to a contiguous bucket
    // chunk WITHIN its direction region so user/item work stays balanced.
    unsigned orig = blockIdx.x;
    unsigned bkt;
    if (orig < NBU_U) {
        const unsigned q = NBU_U / 8u, rem = NBU_U % 8u;
        unsigned x = orig & 7u, off = orig >> 3;
        bkt = (x < rem ? x * (q + 1u) : rem * (q + 1u) + (x - rem) * q) + off;
    } else {
        unsigned o = orig - NBU_U;
        const unsigned q = NBU_I / 8u, rem = NBU_I % 8u;
        unsigned x = o & 7u, off = o >> 3;
        bkt = NBU_U + (x < rem ? x * (q + 1u) : rem * (q + 1u) + (x - rem) * q) + off;
    }

    bool isU = bkt < NBU_U;
    int j = isU ? (int)bkt : (int)bkt - NBU_U;
    unsigned N = isU ? U : M;
    unsigned NSRC = isU ? M : U;  // src feature table rows per relation
    const float* fsrc = isU ? fsrc_u : fsrc_i;

    unsigned sbase = isU ? 0u : (unsigned)OFFI;
    unsigned lo = S[sbase + (unsigned)j * NBLK];
    unsigned hi = (!isU && j + 1 == NBU_I) ? (unsigned)(2 * TE)
                                           : S[sbase + (unsigned)(j + 1) * NBLK];

    for (int t = threadIdx.x; t < NKEY * F; t += BSZ) acc[t] = 0.f;
    unsigned keybase = (unsigned)j * NKEY;
    if (threadIdx.x < NKEY) {
        int t = threadIdx.x;
        cnt[t] = 0.f;
        unsigned key = keybase + (unsigned)t;
        unsigned r = (key < (unsigned)R * N) ? key / N : 0u;
        rbase[t] = r * NSRC;
    }
    __syncthreads();

    unsigned e = lo + threadIdx.x;
    for (; e + 3u * BSZ < hi; e += 4u * BSZ) {
        unsigned pay0 = sorted[e];
        unsigned pay1 = sorted[e + BSZ];
        unsigned pay2 = sorted[e + 2u * BSZ];
        unsigned pay3 = sorted[e + 3u * BSZ];
        unsigned l0 = pay0 & 127u, s0 = pay0 >> 7;
        unsigned l1 = pay1 & 127u, s1 = pay1 >> 7;
        unsigned l2 = pay2 & 127u, s2 = pay2 >> 7;
        unsigned l3 = pay3 & 127u, s3 = pay3 >> 7;
        const float2* r0 = (const float2*)(fsrc + (size_t)(rbase[l0] + s0) * F);
        const float2* r1 = (const float2*)(fsrc + (size_t)(rbase[l1] + s1) * F);
        const float2* r2 = (const float2*)(fsrc + (size_t)(rbase[l2] + s2) * F);
        const float2* r3 = (const float2*)(fsrc + (size_t)(rbase[l3] + s3) * F);
        float2 v0[5], v1[5], v2[5], v3[5];
#pragma unroll
        for (int k = 0; k < 5; k++) v0[k] = r0[k];
#pragma unroll
        for (int k = 0; k < 5; k++) v1[k] = r1[k];
#pragma unroll
        for (int k = 0; k < 5; k++) v2[k] = r2[k];
#pragma unroll
        for (int k = 0; k < 5; k++) v3[k] = r3[k];
        float* a0 = acc + l0 * F;
        float* a1 = acc + l1 * F;
        float* a2 = acc + l2 * F;
        float* a3 = acc + l3 * F;
#pragma unroll
        for (int k = 0; k < 5; k++) {
            atomicAdd(a0 + 2 * k, v0[k].x);
            atomicAdd(a0 + 2 * k + 1, v0[k].y);
        }
        atomicAdd(&cnt[l0], 1.f);
#pragma unroll
        for (int k = 0; k < 5; k++) {
            atomicAdd(a1 + 2 * k, v1[k].x);
            atomicAdd(a1 + 2 * k + 1, v1[k].y);
        }
        atomicAdd(&cnt[l1], 1.f);
#pragma unroll
        for (int k = 0; k < 5; k++) {
            atomicAdd(a2 + 2 * k, v2[k].x);
            atomicAdd(a2 + 2 * k + 1, v2[k].y);
        }
        atomicAdd(&cnt[l2], 1.f);
#pragma unroll
        for (int k = 0; k < 5; k++) {
            atomicAdd(a3 + 2 * k, v3[k].x);
            atomicAdd(a3 + 2 * k + 1, v3[k].y);
        }
        atomicAdd(&cnt[l3], 1.f);
    }
    for (; e < hi; e += BSZ) {
        unsigned pay = sorted[e];
        unsigned local = pay & 127u;
        unsigned src = pay >> 7;
        const float2* row = (const float2*)(fsrc + (size_t)(rbase[local] + src) * F);
        float* a = acc + local * F;
#pragma unroll
        for (int k = 0; k < 5; k++) {
            float2 v = row[k];
            atomicAdd(a + 2 * k, v.x);
            atomicAdd(a + 2 * k + 1, v.y);
        }
        atomicAdd(&cnt[local], 1.f);
    }
    __syncthreads();

    const float* fdst = isU ? fdst_u : fdst_i;
    const float* wsf = isU ? wsf_u : wsf_i;
    const float* wnf = isU ? wnf_u : wnf_i;
    const float* bia = isU ? bia_u : bia_i;
    float* out = isU ? out_u : out_i;

    for (int o = threadIdx.x; o < NKEY * D; o += BSZ) {
        int local = o / D, d = o - local * D;
        unsigned key = keybase + (unsigned)local;
        if (key >= (unsigned)(R)*N) continue;  // tail bucket beyond keyspace
        unsigned r = key / N, n = key - r * N;
        float inv = 1.f / fmaxf(cnt[local], 1.f);
        const float* fd = fdst + ((size_t)r * N + n) * F;
        const float* a = acc + local * F;
        const float* wsp = wsf + (size_t)r * F * D + d;
        const float* wnp = wnf + (size_t)r * F * D + d;
        float o1 = bia[r * D + d], o2 = 0.f;
#pragma unroll
        for (int f = 0; f < F; f++) {
            o1 += fd[f] * wsp[(size_t)f * D];
            o2 += a[f] * wnp[(size_t)f * D];
        }
        out[(size_t)n * (R * D) + r * D + d] = o1 + o2 * inv;
    }
}

// ======================= round-1 fallback (small ws) =======================
#define SUM_I_OFF 0
#define CNT_I_OFF ((size_t)R * M * F)
#define SUM_U_OFF (CNT_I_OFF + (size_t)R * M)
#define CNT_U_OFF (SUM_U_OFF + (size_t)R * U * F)
#define WS_FLOATS (CNT_U_OFF + (size_t)R * U)

__global__ void scatter_edges(const int* __restrict__ esrc, const int* __restrict__ edst,
                              const float* __restrict__ feat_u_fwd,
                              const float* __restrict__ feat_i_rev, float* __restrict__ ws) {
    float* sum_i = ws + SUM_I_OFF;
    float* cnt_i = ws + CNT_I_OFF;
    float* sum_u = ws + SUM_U_OFF;
    float* cnt_u = ws + CNT_U_OFF;
    const int total = R * E;
    for (int idx = blockIdx.x * blockDim.x + threadIdx.x; idx < total;
         idx += gridDim.x * blockDim.x) {
        int r = idx / E;
        int s = esrc[idx], d = edst[idx];
        const float* fu = feat_u_fwd + ((size_t)r * U + s) * F;
        const float* fi = feat_i_rev + ((size_t)r * M + d) * F;
        float* si = sum_i + ((size_t)r * M + d) * F;
        float* su = sum_u + ((size_t)r * U + s) * F;
#pragma unroll
        for (int f = 0; f < F; ++f) {
            atomicAdd(si + f, fu[f]);
            atomicAdd(su + f, fi[f]);
        }
        atomicAdd(cnt_i + (size_t)r * M + d, 1.0f);
        atomicAdd(cnt_u + (size_t)r * U + s, 1.0f);
    }
}

__global__ void finalize_nodes(int N, const float* __restrict__ feat_dst,
                               const float* __restrict__ w_self, const float* __restrict__ w_neigh,
                               const float* __restrict__ bias, const float* __restrict__ sum,
                               const float* __restrict__ cnt, float* __restrict__ out) {
    int idx = blockIdx.x * blockDim.x + threadIdx.x;
    int total = N * R * D;
    if (idx >= total) return;
    int n = idx / (R * D);
    int rd = idx - n * (R * D);
    int r = rd / D;
    int d = rd - r * D;
    const float* fd = feat_dst + ((size_t)r * N + n) * F;
    const float* sn = sum + ((size_t)r * N + n) * F;
    float inv = 1.0f / fmaxf(cnt[(size_t)r * N + n], 1.0f);
    const float* wsp = w_self + (size_t)r * F * D + d;
    const float* wnp = w_neigh + (size_t)r * F * D + d;
    float acc_self = bias[r * D + d];
    float acc_n = 0.0f;
#pragma unroll
    for (int f = 0; f < F; ++f) {
        acc_self += fd[f] * wsp[(size_t)f * D];
        acc_n += sn[f] * wnp[(size_t)f * D];
    }
    out[idx] = acc_self + acc_n * inv;
}

// ======================= launch =======================
extern "C" void kernel_launch(void* const* d_in, const int* in_sizes, int n_in,
                              void* d_out, int out_size, void* d_ws, size_t ws_size,
                              hipStream_t stream) {
    const int* edges_src = (const int*)d_in[0];
    const int* edges_dst = (const int*)d_in[1];
    const float* feat_u_fwd = (const float*)d_in[2];
    const float* feat_i_fwd = (const float*)d_in[3];
    const float* feat_i_rev = (const float*)d_in[4];
    const float* feat_u_rev = (const float*)d_in[5];
    const float* w_self_fwd = (const float*)d_in[6];
    const float* w_neigh_fwd = (const float*)d_in[7];
    const float* b_fwd = (const float*)d_in[8];
    const float* w_self_rev = (const float*)d_in[9];
    const float* w_neigh_rev = (const float*)d_in[10];
    const float* b_rev = (const float*)d_in[11];

    float* out = (float*)d_out;
    float* out_u = out;
    float* out_i = out + (size_t)U * R * D;

    // sorted (2*TE) + S/ghist in-place (GTOT) + psum (NS1 rounded up)
    size_t need = ((size_t)2 * TE + (size_t)GTOT + 2048ull) * 4ull;  // ~86 MB
    if (ws_size >= need) {
        unsigned* sorted = (unsigned*)d_ws;            // 2*TE
        unsigned* S = sorted + (size_t)2 * TE;         // GTOT (ghist scanned in place)
        unsigned* psum = S + GTOT;                     // 2048

        phaseA<<<NBLK, BSZ, 0, stream>>>(edges_src, edges_dst, S);
        scan1<<<NS1, BSZ, 0, stream>>>(S, psum);
        scan2<<<1, BSZ, 0, stream>>>(psum);
        scan3<<<NS1, BSZ, 0, stream>>>(S, psum);
        phaseC<<<NBLK, BSZ, 0, stream>>>(edges_src, edges_dst, S, sorted);
        phaseD<<<NBU_T, BSZ, 0, stream>>>(sorted, S,
                                          feat_i_rev, feat_u_rev, w_self_rev, w_neigh_rev, b_rev,
                                          feat_u_fwd, feat_i_fwd, w_self_fwd, w_neigh_fwd, b_fwd,
                                          out_u, out_i);
    } else {
        // fallback: round-1 global-atomic path
        float* ws = (float*)d_ws;
        hipMemsetAsync(d_ws, 0, WS_FLOATS * sizeof(float), stream);
        scatter_edges<<<4096, 256, 0, stream>>>(edges_src, edges_dst, feat_u_fwd, feat_i_rev, ws);
        finalize_nodes<<<(U * R * D + 255) / 256, 256, 0, stream>>>(
            U, feat_u_rev, w_self_rev, w_neigh_rev, b_rev, ws + SUM_U_OFF, ws + CNT_U_OFF, out_u);
        finalize_nodes<<<(M * R * D + 255) / 256, 256, 0, stream>>>(
            M, feat_i_fwd, w_self_fwd, w_neigh_fwd, b_fwd, ws + SUM_I_OFF, ws + CNT_I_OFF, out_i);
    }
}

// Round 8
// 717.523 us; speedup vs baseline: 2.7494x; 1.9981x over previous
//
#include <hip/hip_runtime.h>

#define R 5
#define U 100000
#define M 50000
#define E 2000000
#define F 10
#define D 50

#define TE (R * E)                      // 10,000,000 edges per direction
#define NBLK 256                        // phase A/C block count
#define CHUNK ((TE + NBLK - 1) / NBLK)  // 39,063 edges per block
#define BSZ 256

#define NKEY 128                        // keys per bucket (local id fits 7 bits)
#define KS_U (R * U)                    // 500,000 user keys
#define KS_I (R * M)                    // 250,000 item keys
#define NBU_U ((KS_U + NKEY - 1) / NKEY)  // 3907 user buckets
#define NBU_I ((KS_I + NKEY - 1) / NKEY)  // 1954 item buckets
#define NBU_T (NBU_U + NBU_I)             // 5861
#define OFFI (NBU_U * NBLK)               // item region start in S
#define GTOT (OFFI + NBU_I * NBLK)        // 1,500,416
#define NS1 ((GTOT + 1023) / 1024)        // scan blocks
#define S2K ((NS1 + 255) / 256)           // entries/thread in scan2

#define CAP 6656                        // max edges per bucket (avg 5120 + 21 sigma)
#define ASTR 11                         // acc stride (gcd(11,32)=1 -> all banks)

// ======================= bucketed counting-sort path =======================

__global__ __launch_bounds__(BSZ) void phaseA(const int* __restrict__ esrc,
                                              const int* __restrict__ edst,
                                              unsigned* __restrict__ ghist) {
    __shared__ unsigned hist[NBU_T];
    for (int i = threadIdx.x; i < NBU_T; i += BSZ) hist[i] = 0;
    __syncthreads();
    int b = blockIdx.x;
    int lo = b * CHUNK, hi = min(lo + CHUNK, TE);
    for (int i = lo + threadIdx.x; i < hi; i += BSZ) {
        unsigned r = (unsigned)i / (unsigned)E;
        int s = esrc[i], d = edst[i];
        unsigned ku = r * U + (unsigned)s;
        unsigned ki = r * M + (unsigned)d;
        atomicAdd(&hist[ku >> 7], 1u);
        atomicAdd(&hist[NBU_U + (ki >> 7)], 1u);
    }
    __syncthreads();
    for (int j = threadIdx.x; j < NBU_T; j += BSZ) {
        unsigned idx = (j < NBU_U) ? (unsigned)j * NBLK + b
                                   : OFFI + (unsigned)(j - NBU_U) * NBLK + b;
        ghist[idx] = hist[j];
    }
}

// Exclusive scan over ghist IN PLACE (S == ghist), 3 kernels.
__global__ __launch_bounds__(BSZ) void scan1(unsigned* __restrict__ S,
                                             unsigned* __restrict__ psum) {
    __shared__ unsigned sh[BSZ];
    int base = blockIdx.x * 1024 + threadIdx.x * 4;
    unsigned v[4], tsum = 0;
    for (int k = 0; k < 4; k++) {
        int i = base + k;
        v[k] = (i < GTOT) ? S[i] : 0u;
        tsum += v[k];
    }
    sh[threadIdx.x] = tsum;
    __syncthreads();
    for (int off = 1; off < BSZ; off <<= 1) {
        unsigned t = (threadIdx.x >= off) ? sh[threadIdx.x - off] : 0u;
        __syncthreads();
        sh[threadIdx.x] += t;
        __syncthreads();
    }
    unsigned ex = sh[threadIdx.x] - tsum;
    for (int k = 0; k < 4; k++) {
        int i = base + k;
        if (i < GTOT) S[i] = ex;
        ex += v[k];
    }
    if (threadIdx.x == BSZ - 1) psum[blockIdx.x] = sh[BSZ - 1];
}

__global__ __launch_bounds__(BSZ) void scan2(unsigned* __restrict__ psum) {
    __shared__ unsigned sh[BSZ];
    unsigned v[S2K], tsum = 0;
    int base = threadIdx.x * S2K;
    for (int k = 0; k < S2K; k++) {
        int i = base + k;
        v[k] = (i < NS1) ? psum[i] : 0u;
        tsum += v[k];
    }
    sh[threadIdx.x] = tsum;
    __syncthreads();
    for (int off = 1; off < BSZ; off <<= 1) {
        unsigned t = (threadIdx.x >= off) ? sh[threadIdx.x - off] : 0u;
        __syncthreads();
        sh[threadIdx.x] += t;
        __syncthreads();
    }
    unsigned ex = sh[threadIdx.x] - tsum;
    for (int k = 0; k < S2K; k++) {
        int i = base + k;
        if (i < NS1) psum[i] = ex;
        ex += v[k];
    }
}

__global__ __launch_bounds__(BSZ) void scan3(unsigned* __restrict__ S,
                                             const unsigned* __restrict__ psum) {
    unsigned add = psum[blockIdx.x];
    int base = blockIdx.x * 1024 + threadIdx.x * 4;
    for (int k = 0; k < 4; k++) {
        int i = base + k;
        if (i < GTOT) S[i] += add;
    }
}

// Scatter edges into bucket-grouped payload array. LDS cursor atomics only.
// payload = local_node(7b) | src_id(<<7).
__global__ __launch_bounds__(BSZ) void phaseC(const int* __restrict__ esrc,
                                              const int* __restrict__ edst,
                                              const unsigned* __restrict__ S,
                                              unsigned* __restrict__ sorted) {
    __shared__ unsigned cur[NBU_T];
    int b = blockIdx.x;
    for (int j = threadIdx.x; j < NBU_T; j += BSZ) {
        unsigned idx = (j < NBU_U) ? (unsigned)j * NBLK + b
                                   : OFFI + (unsigned)(j - NBU_U) * NBLK + b;
        cur[j] = S[idx];
    }
    __syncthreads();
    int lo = b * CHUNK, hi = min(lo + CHUNK, TE);
    for (int i = lo + threadIdx.x; i < hi; i += BSZ) {
        unsigned r = (unsigned)i / (unsigned)E;
        int s = esrc[i], d = edst[i];
        unsigned ku = r * U + (unsigned)s;
        unsigned ki = r * M + (unsigned)d;
        unsigned pu = atomicAdd(&cur[ku >> 7], 1u);
        sorted[pu] = (ku & 127u) | ((unsigned)d << 7);
        unsigned pi = atomicAdd(&cur[NBU_U + (ki >> 7)], 1u);
        sorted[pi] = (ki & 127u) | ((unsigned)s << 7);
    }
}

// phaseD v4: in-LDS counting sort by local key, then register segmented
// reduction (2-deep pipelined gathers, flush only at run boundaries).
// Eliminates the 11 per-edge LDS atomics of v2/v3 (suspected binding cost:
// stride-10 / same-address atomic RMW serialization invisible to
// SQ_LDS_BANK_CONFLICT).
__global__ __launch_bounds__(BSZ) void phaseD(
    const unsigned* __restrict__ sorted, const unsigned* __restrict__ S,
    const float* __restrict__ fsrc_u, const float* __restrict__ fdst_u,
    const float* __restrict__ wsf_u, const float* __restrict__ wnf_u,
    const float* __restrict__ bia_u,
    const float* __restrict__ fsrc_i, const float* __restrict__ fdst_i,
    const float* __restrict__ wsf_i, const float* __restrict__ wnf_i,
    const float* __restrict__ bia_i,
    float* __restrict__ out_u, float* __restrict__ out_i) {
    __shared__ unsigned sbuf[CAP];       // key-sorted payloads
    __shared__ float acc[NKEY * ASTR];   // per-key neighbor sums (stride 11)
    __shared__ unsigned hist[NKEY];      // per-key degree
    __shared__ unsigned cur[NKEY];       // scan + scatter cursors
    __shared__ unsigned rbase[NKEY];     // r(key) * NSRC

    // per-direction bijective XCD swizzle: balanced edges per XCD AND
    // contiguous per-XCD bucket chunk (keeps gather slice L2-resident).
    unsigned orig = blockIdx.x;
    unsigned bkt;
    if (orig < NBU_U) {
        const unsigned q = NBU_U / 8u, rem = NBU_U % 8u;
        unsigned x = orig & 7u, off = orig >> 3;
        bkt = (x < rem ? x * (q + 1u) : rem * (q + 1u) + (x - rem) * q) + off;
    } else {
        unsigned o = orig - NBU_U;
        const unsigned q = NBU_I / 8u, rem = NBU_I % 8u;
        unsigned x = o & 7u, off = o >> 3;
        bkt = NBU_U + (x < rem ? x * (q + 1u) : rem * (q + 1u) + (x - rem) * q) + off;
    }

    bool isU = bkt < NBU_U;
    int j = isU ? (int)bkt : (int)bkt - NBU_U;
    unsigned N = isU ? U : M;
    unsigned NSRC = isU ? M : U;
    const float* fsrc = isU ? fsrc_u : fsrc_i;

    unsigned sbase = isU ? 0u : (unsigned)OFFI;
    unsigned lo = S[sbase + (unsigned)j * NBLK];
    unsigned hi = (!isU && j + 1 == NBU_I) ? (unsigned)(2 * TE)
                                           : S[sbase + (unsigned)(j + 1) * NBLK];
    unsigned len = hi - lo;
    unsigned keybase = (unsigned)j * NKEY;
    int tid = threadIdx.x;

    for (int t = tid; t < NKEY * ASTR; t += BSZ) acc[t] = 0.f;
    if (tid < NKEY) {
        hist[tid] = 0u;
        unsigned key = keybase + (unsigned)tid;
        unsigned r = (key < (unsigned)R * N) ? key / N : 0u;
        rbase[tid] = r * NSRC;
    }
    __syncthreads();

    if (len <= CAP) {
        // ---- step 1: per-key histogram (1 LDS atomic / edge) ----
        for (unsigned e = lo + tid; e < hi; e += BSZ)
            atomicAdd(&hist[sorted[e] & 127u], 1u);
        __syncthreads();
        // ---- step 2: exclusive scan of hist -> cur (uniform barriers only) ----
        if (tid < NKEY) cur[tid] = hist[tid];
        __syncthreads();
        for (int off = 1; off < NKEY; off <<= 1) {
            unsigned t = 0;
            if (tid < NKEY && tid >= off) t = cur[tid - off];
            __syncthreads();
            if (tid < NKEY && tid >= off) cur[tid] += t;
            __syncthreads();
        }
        // inclusive -> exclusive: each thread touches only its own slot
        if (tid < NKEY) cur[tid] -= hist[tid];
        __syncthreads();
        // ---- step 3: scatter into key-sorted LDS array ----
        for (unsigned e = lo + tid; e < hi; e += BSZ) {
            unsigned pay = sorted[e];
            unsigned pos = atomicAdd(&cur[pay & 127u], 1u);
            sbuf[pos] = pay;
        }
        __syncthreads();
        // ---- step 4: register segmented reduce over equal slices ----
        unsigned L = (len + BSZ - 1) / BSZ;
        unsigned i0 = (unsigned)tid * L;
        unsigned i1 = min(i0 + L, len);
        if (i0 < i1) {
            int curKey = -1;
            float A0 = 0, A1 = 0, A2 = 0, A3 = 0, A4 = 0,
                  A5 = 0, A6 = 0, A7 = 0, A8 = 0, A9 = 0;
#define FLUSH_ACC()                                                        \
    do {                                                                   \
        if (curKey >= 0) {                                                 \
            float* ap = acc + curKey * ASTR;                               \
            atomicAdd(ap + 0, A0); atomicAdd(ap + 1, A1);                  \
            atomicAdd(ap + 2, A2); atomicAdd(ap + 3, A3);                  \
            atomicAdd(ap + 4, A4); atomicAdd(ap + 5, A5);                  \
            atomicAdd(ap + 6, A6); atomicAdd(ap + 7, A7);                  \
            atomicAdd(ap + 8, A8); atomicAdd(ap + 9, A9);                  \
        }                                                                  \
    } while (0)
#define ZERO_ACC() A0=A1=A2=A3=A4=A5=A6=A7=A8=A9=0.f
            unsigned i = i0;
            for (; i + 1 < i1; i += 2) {
                unsigned p0 = sbuf[i], p1 = sbuf[i + 1];
                unsigned k0 = p0 & 127u, s0 = p0 >> 7;
                unsigned k1 = p1 & 127u, s1 = p1 >> 7;
                const float2* r0 = (const float2*)(fsrc + (size_t)(rbase[k0] + s0) * F);
                const float2* r1 = (const float2*)(fsrc + (size_t)(rbase[k1] + s1) * F);
                float2 x0 = r0[0], x1 = r0[1], x2 = r0[2], x3 = r0[3], x4 = r0[4];
                float2 y0 = r1[0], y1 = r1[1], y2 = r1[2], y3 = r1[3], y4 = r1[4];
                if ((int)k0 != curKey) { FLUSH_ACC(); curKey = (int)k0; ZERO_ACC(); }
                A0 += x0.x; A1 += x0.y; A2 += x1.x; A3 += x1.y; A4 += x2.x;
                A5 += x2.y; A6 += x3.x; A7 += x3.y; A8 += x4.x; A9 += x4.y;
                if ((int)k1 != curKey) { FLUSH_ACC(); curKey = (int)k1; ZERO_ACC(); }
                A0 += y0.x; A1 += y0.y; A2 += y1.x; A3 += y1.y; A4 += y2.x;
                A5 += y2.y; A6 += y3.x; A7 += y3.y; A8 += y4.x; A9 += y4.y;
            }
            if (i < i1) {
                unsigned p0 = sbuf[i];
                unsigned k0 = p0 & 127u, s0 = p0 >> 7;
                const float2* r0 = (const float2*)(fsrc + (size_t)(rbase[k0] + s0) * F);
                float2 x0 = r0[0], x1 = r0[1], x2 = r0[2], x3 = r0[3], x4 = r0[4];
                if ((int)k0 != curKey) { FLUSH_ACC(); curKey = (int)k0; ZERO_ACC(); }
                A0 += x0.x; A1 += x0.y; A2 += x1.x; A3 += x1.y; A4 += x2.x;
                A5 += x2.y; A6 += x3.x; A7 += x3.y; A8 += x4.x; A9 += x4.y;
            }
            FLUSH_ACC();
#undef FLUSH_ACC
#undef ZERO_ACC
        }
    } else {
        // overflow fallback (statistically unreachable): per-edge atomics
        for (unsigned e = lo + tid; e < hi; e += BSZ) {
            unsigned pay = sorted[e];
            unsigned l = pay & 127u, s = pay >> 7;
            const float2* row = (const float2*)(fsrc + (size_t)(rbase[l] + s) * F);
            float* a = acc + l * ASTR;
#pragma unroll
            for (int k = 0; k < 5; k++) {
                float2 v = row[k];
                atomicAdd(a + 2 * k, v.x);
                atomicAdd(a + 2 * k + 1, v.y);
            }
            atomicAdd(&hist[l], 1u);
        }
    }
    __syncthreads();

    // ---- epilogue: fused projection ----
    const float* fdst = isU ? fdst_u : fdst_i;
    const float* wsf = isU ? wsf_u : wsf_i;
    const float* wnf = isU ? wnf_u : wnf_i;
    const float* bia = isU ? bia_u : bia_i;
    float* out = isU ? out_u : out_i;

    for (int o = tid; o < NKEY * D; o += BSZ) {
        int local = o / D, d = o - local * D;
        unsigned key = keybase + (unsigned)local;
        if (key >= (unsigned)(R)*N) continue;
        unsigned r = key / N, n = key - r * N;
        float inv = 1.f / fmaxf((float)hist[local], 1.f);
        const float* fd = fdst + ((size_t)r * N + n) * F;
        const float* a = acc + local * ASTR;
        const float* wsp = wsf + (size_t)r * F * D + d;
        const float* wnp = wnf + (size_t)r * F * D + d;
        float o1 = bia[r * D + d], o2 = 0.f;
#pragma unroll
        for (int f = 0; f < F; f++) {
            o1 += fd[f] * wsp[(size_t)f * D];
            o2 += a[f] * wnp[(size_t)f * D];
        }
        out[(size_t)n * (R * D) + r * D + d] = o1 + o2 * inv;
    }
}

// ======================= round-1 fallback (small ws) =======================
#define SUM_I_OFF 0
#define CNT_I_OFF ((size_t)R * M * F)
#define SUM_U_OFF (CNT_I_OFF + (size_t)R * M)
#define CNT_U_OFF (SUM_U_OFF + (size_t)R * U * F)
#define WS_FLOATS (CNT_U_OFF + (size_t)R * U)

__global__ void scatter_edges(const int* __restrict__ esrc, const int* __restrict__ edst,
                              const float* __restrict__ feat_u_fwd,
                              const float* __restrict__ feat_i_rev, float* __restrict__ ws) {
    float* sum_i = ws + SUM_I_OFF;
    float* cnt_i = ws + CNT_I_OFF;
    float* sum_u = ws + SUM_U_OFF;
    float* cnt_u = ws + CNT_U_OFF;
    const int total = R * E;
    for (int idx = blockIdx.x * blockDim.x + threadIdx.x; idx < total;
         idx += gridDim.x * blockDim.x) {
        int r = idx / E;
        int s = esrc[idx], d = edst[idx];
        const float* fu = feat_u_fwd + ((size_t)r * U + s) * F;
        const float* fi = feat_i_rev + ((size_t)r * M + d) * F;
        float* si = sum_i + ((size_t)r * M + d) * F;
        float* su = sum_u + ((size_t)r * U + s) * F;
#pragma unroll
        for (int f = 0; f < F; ++f) {
            atomicAdd(si + f, fu[f]);
            atomicAdd(su + f, fi[f]);
        }
        atomicAdd(cnt_i + (size_t)r * M + d, 1.0f);
        atomicAdd(cnt_u + (size_t)r * U + s, 1.0f);
    }
}

__global__ void finalize_nodes(int N, const float* __restrict__ feat_dst,
                               const float* __restrict__ w_self, const float* __restrict__ w_neigh,
                               const float* __restrict__ bias, const float* __restrict__ sum,
                               const float* __restrict__ cnt, float* __restrict__ out) {
    int idx = blockIdx.x * blockDim.x + threadIdx.x;
    int total = N * R * D;
    if (idx >= total) return;
    int n = idx / (R * D);
    int rd = idx - n * (R * D);
    int r = rd / D;
    int d = rd - r * D;
    const float* fd = feat_dst + ((size_t)r * N + n) * F;
    const float* sn = sum + ((size_t)r * N + n) * F;
    float inv = 1.0f / fmaxf(cnt[(size_t)r * N + n], 1.0f);
    const float* wsp = w_self + (size_t)r * F * D + d;
    const float* wnp = w_neigh + (size_t)r * F * D + d;
    float acc_self = bias[r * D + d];
    float acc_n = 0.0f;
#pragma unroll
    for (int f = 0; f < F; ++f) {
        acc_self += fd[f] * wsp[(size_t)f * D];
        acc_n += sn[f] * wnp[(size_t)f * D];
    }
    out[idx] = acc_self + acc_n * inv;
}

// ======================= launch =======================
extern "C" void kernel_launch(void* const* d_in, const int* in_sizes, int n_in,
                              void* d_out, int out_size, void* d_ws, size_t ws_size,
                              hipStream_t stream) {
    const int* edges_src = (const int*)d_in[0];
    const int* edges_dst = (const int*)d_in[1];
    const float* feat_u_fwd = (const float*)d_in[2];
    const float* feat_i_fwd = (const float*)d_in[3];
    const float* feat_i_rev = (const float*)d_in[4];
    const float* feat_u_rev = (const float*)d_in[5];
    const float* w_self_fwd = (const float*)d_in[6];
    const float* w_neigh_fwd = (const float*)d_in[7];
    const float* b_fwd = (const float*)d_in[8];
    const float* w_self_rev = (const float*)d_in[9];
    const float* w_neigh_rev = (const float*)d_in[10];
    const float* b_rev = (const float*)d_in[11];

    float* out = (float*)d_out;
    float* out_u = out;
    float* out_i = out + (size_t)U * R * D;

    // sorted (2*TE) + S/ghist in-place (GTOT) + psum (2048)
    size_t need = ((size_t)2 * TE + (size_t)GTOT + 2048ull) * 4ull;  // ~86 MB
    if (ws_size >= need) {
        unsigned* sorted = (unsigned*)d_ws;            // 2*TE
        unsigned* S = sorted + (size_t)2 * TE;         // GTOT (scanned in place)
        unsigned* psum = S + GTOT;                     // 2048

        phaseA<<<NBLK, BSZ, 0, stream>>>(edges_src, edges_dst, S);
        scan1<<<NS1, BSZ, 0, stream>>>(S, psum);
        scan2<<<1, BSZ, 0, stream>>>(psum);
        scan3<<<NS1, BSZ, 0, stream>>>(S, psum);
        phaseC<<<NBLK, BSZ, 0, stream>>>(edges_src, edges_dst, S, sorted);
        phaseD<<<NBU_T, BSZ, 0, stream>>>(sorted, S,
                                          feat_i_rev, feat_u_rev, w_self_rev, w_neigh_rev, b_rev,
                                          feat_u_fwd, feat_i_fwd, w_self_fwd, w_neigh_fwd, b_fwd,
                                          out_u, out_i);
    } else {
        // fallback: round-1 global-atomic path
        float* ws = (float*)d_ws;
        hipMemsetAsync(d_ws, 0, WS_FLOATS * sizeof(float), stream);
        scatter_edges<<<4096, 256, 0, stream>>>(edges_src, edges_dst, feat_u_fwd, feat_i_rev, ws);
        finalize_nodes<<<(U * R * D + 255) / 256, 256, 0, stream>>>(
            U, feat_u_rev, w_self_rev, w_neigh_rev, b_rev, ws + SUM_U_OFF, ws + CNT_U_OFF, out_u);
        finalize_nodes<<<(M * R * D + 255) / 256, 256, 0, stream>>>(
            M, feat_i_fwd, w_self_fwd, w_neigh_fwd, b_fwd, ws + SUM_I_OFF, ws + CNT_I_OFF, out_i);
    }
}